// Round 1
// baseline (258.439 us; speedup 1.0000x reference)
//
#include <hip/hip_runtime.h>

#define HH 16
#define RED_VALS 34  // 16 top(g.p) + 16 (y.p) + cur + gg

__global__ __launch_bounds__(256) void lbfgs_reduce(
    const float* __restrict__ p, const float* __restrict__ y,
    const float* __restrict__ g, const int* __restrict__ idxp,
    float* __restrict__ partials, int n) {
  const int is = idxp[0];
  const int hidx = ((is - 1) % HH + HH) % HH;
  float acc[RED_VALS];
#pragma unroll
  for (int j = 0; j < RED_VALS; ++j) acc[j] = 0.f;

  const int tid = blockIdx.x * blockDim.x + threadIdx.x;
  const int nth = gridDim.x * blockDim.x;
  const int nchunk = n >> 2;
  const float4* __restrict__ p4 = reinterpret_cast<const float4*>(p);

  for (int c = tid; c < nchunk; c += nth) {
    float4 pv = p4[c];
#pragma unroll
    for (int i = 0; i < HH; ++i) {
      const float4 gv = reinterpret_cast<const float4*>(g + (size_t)i * n)[c];
      const float4 yv = reinterpret_cast<const float4*>(y + (size_t)i * n)[c];
      acc[i]      += gv.x * pv.x + gv.y * pv.y + gv.z * pv.z + gv.w * pv.w;
      acc[HH + i] += yv.x * pv.x + yv.y * pv.y + yv.z * pv.z + yv.w * pv.w;
      if (i == hidx) {
        acc[32] += yv.x * gv.x + yv.y * gv.y + yv.z * gv.z + yv.w * gv.w;
        acc[33] += gv.x * gv.x + gv.y * gv.y + gv.z * gv.z + gv.w * gv.w;
      }
    }
  }
  // scalar tail (n not multiple of 4)
  for (int c = (nchunk << 2) + tid; c < n; c += nth) {
    float pv = p[c];
#pragma unroll
    for (int i = 0; i < HH; ++i) {
      float gv = g[(size_t)i * n + c];
      float yv = y[(size_t)i * n + c];
      acc[i] += gv * pv;
      acc[HH + i] += yv * pv;
      if (i == hidx) { acc[32] += yv * gv; acc[33] += gv * gv; }
    }
  }
  // wave(64) shuffle reduce, then cross-wave via LDS
#pragma unroll
  for (int j = 0; j < RED_VALS; ++j) {
    float v = acc[j];
#pragma unroll
    for (int off = 32; off > 0; off >>= 1) v += __shfl_down(v, off);
    acc[j] = v;
  }
  __shared__ float red[4][RED_VALS];
  const int wave = threadIdx.x >> 6, lane = threadIdx.x & 63;
  if (lane == 0) {
#pragma unroll
    for (int j = 0; j < RED_VALS; ++j) red[wave][j] = acc[j];
  }
  __syncthreads();
  if (threadIdx.x < RED_VALS) {
    float s = red[0][threadIdx.x] + red[1][threadIdx.x] +
              red[2][threadIdx.x] + red[3][threadIdx.x];
    partials[(size_t)blockIdx.x * RED_VALS + threadIdx.x] = s;
  }
}

__global__ __launch_bounds__(256) void lbfgs_solve(
    const float* __restrict__ partials, int nblk,
    const float* __restrict__ Lmat, const float* __restrict__ diag,
    const float* __restrict__ sinner, const int* __restrict__ idxp,
    float* __restrict__ coeff) {
  __shared__ float sums[RED_VALS];
  __shared__ float wred[RED_VALS][4];
  const int wave = threadIdx.x >> 6, lane = threadIdx.x & 63;
  for (int j = 0; j < RED_VALS; ++j) {
    float v = 0.f;
    for (int b = threadIdx.x; b < nblk; b += 256)
      v += partials[(size_t)b * RED_VALS + j];
#pragma unroll
    for (int off = 32; off > 0; off >>= 1) v += __shfl_down(v, off);
    if (lane == 0) wred[j][wave] = v;
  }
  __syncthreads();
  if (threadIdx.x < RED_VALS)
    sums[threadIdx.x] = wred[threadIdx.x][0] + wred[threadIdx.x][1] +
                        wred[threadIdx.x][2] + wred[threadIdx.x][3];
  __syncthreads();

  __shared__ float Lsh[HH][HH];
  __shared__ float dd[HH], sqd[HH];
  __shared__ float Jsq[HH][HH];
  __shared__ float gamma_s;
  __shared__ float x[2 * HH];
  {
    int i = threadIdx.x >> 4, j = threadIdx.x & 15;
    if (threadIdx.x < 256) Lsh[i][j] = Lmat[i * HH + j];
  }
  if (threadIdx.x < HH) {
    float dv = diag[threadIdx.x];
    float ddv = (dv == 0.f) ? 1.f : dv;
    dd[threadIdx.x] = ddv;
    sqd[threadIdx.x] = sqrtf(ddv);
  }
  if (threadIdx.x == 0) {
    float cur = sums[32], gg = sums[33];
    gamma_s = (cur > 0.f) ? (gg / cur) : 1.f;
  }
  __syncthreads();
  {
    int i = threadIdx.x >> 4, j = threadIdx.x & 15;
    float v = gamma_s * sinner[i * HH + j];
#pragma unroll
    for (int k = 0; k < HH; ++k) v += Lsh[i][k] * Lsh[j][k] / dd[k];
    Jsq[i][j] = v;
  }
  __syncthreads();
  if (threadIdx.x == 0) {
    // in-place lower Cholesky of Jsq (16x16, serial — tiny)
    for (int c = 0; c < HH; ++c) {
      float s = Jsq[c][c];
      for (int k = 0; k < c; ++k) s -= Jsq[c][k] * Jsq[c][k];
      float dv = sqrtf(s);
      Jsq[c][c] = dv;
      float inv = 1.f / dv;
      for (int r = c + 1; r < HH; ++r) {
        float s2 = Jsq[r][c];
        for (int k = 0; k < c; ++k) s2 -= Jsq[r][k] * Jsq[c][k];
        Jsq[r][c] = s2 * inv;
      }
    }
    const int is = idxp[0];
    const int sh = (is <= HH) ? 0 : (is % HH);
    const float gamma = gamma_s;
    // build rolled descent vector
    for (int k = 0; k < HH; ++k) {
      x[k]      = sums[(k + sh) & (HH - 1)];
      x[HH + k] = gamma * sums[HH + ((k + sh) & (HH - 1))];
    }
    // forward solve: low_tri = [[diag(sqd), 0], [-L/sqd_col, J]]
    for (int i = 0; i < HH; ++i) x[i] /= sqd[i];
    for (int i = 0; i < HH; ++i) {
      float s = x[HH + i];
      for (int j = 0; j < HH; ++j) s += (Lsh[i][j] / sqd[j]) * x[j];
      for (int j = 0; j < i; ++j) s -= Jsq[i][j] * x[HH + j];
      x[HH + i] = s / Jsq[i][i];
    }
    // backward solve: upper = low^T with top h rows negated
    for (int i = HH - 1; i >= 0; --i) {
      float s = x[HH + i];
      for (int j = i + 1; j < HH; ++j) s -= Jsq[j][i] * x[HH + j];
      x[HH + i] = s / Jsq[i][i];
    }
    for (int i = 0; i < HH; ++i) {
      float s = x[i];
      for (int j = 0; j < HH; ++j) s -= (Lsh[j][i] / sqd[i]) * x[HH + j];
      x[i] = s / (-sqd[i]);
    }
    // un-roll and emit coefficients (beta pre-scaled by gamma)
    coeff[0] = gamma;
    for (int k = 0; k < HH; ++k) {
      coeff[1 + k]      = x[(k - sh + HH) & (HH - 1)];
      coeff[1 + HH + k] = gamma * x[HH + ((k - sh + HH) & (HH - 1))];
    }
  }
}

__global__ __launch_bounds__(256) void lbfgs_output(
    const float* __restrict__ p, const float* __restrict__ y,
    const float* __restrict__ g, const float* __restrict__ coeff,
    float* __restrict__ out, int n) {
  const float gamma = coeff[0];
  float a[HH], b[HH];
#pragma unroll
  for (int i = 0; i < HH; ++i) {
    a[i] = coeff[1 + i];
    b[i] = coeff[1 + HH + i];
  }
  const int tid = blockIdx.x * blockDim.x + threadIdx.x;
  const int nth = gridDim.x * blockDim.x;
  const int nchunk = n >> 2;
  const float4* __restrict__ p4 = reinterpret_cast<const float4*>(p);
  float4* __restrict__ out4 = reinterpret_cast<float4*>(out);
  for (int c = tid; c < nchunk; c += nth) {
    float4 pv = p4[c];
    float ox = gamma * pv.x, oy = gamma * pv.y;
    float oz = gamma * pv.z, ow = gamma * pv.w;
#pragma unroll
    for (int i = 0; i < HH; ++i) {
      const float4 gv = reinterpret_cast<const float4*>(g + (size_t)i * n)[c];
      const float4 yv = reinterpret_cast<const float4*>(y + (size_t)i * n)[c];
      ox -= a[i] * gv.x + b[i] * yv.x;
      oy -= a[i] * gv.y + b[i] * yv.y;
      oz -= a[i] * gv.z + b[i] * yv.z;
      ow -= a[i] * gv.w + b[i] * yv.w;
    }
    out4[c] = make_float4(ox, oy, oz, ow);
  }
  for (int c = (nchunk << 2) + tid; c < n; c += nth) {
    float pv = p[c];
    float o = gamma * pv;
#pragma unroll
    for (int i = 0; i < HH; ++i)
      o -= a[i] * g[(size_t)i * n + c] + b[i] * y[(size_t)i * n + c];
    out[c] = o;
  }
}

extern "C" void kernel_launch(void* const* d_in, const int* in_sizes, int n_in,
                              void* d_out, int out_size, void* d_ws, size_t ws_size,
                              hipStream_t stream) {
  const float* p      = (const float*)d_in[0];
  const float* y      = (const float*)d_in[1];
  const float* g      = (const float*)d_in[2];
  const float* Lmat   = (const float*)d_in[3];
  const float* diag   = (const float*)d_in[4];
  const float* sinner = (const float*)d_in[5];
  const int*   idxp   = (const int*)d_in[6];
  float* out = (float*)d_out;
  float* wsf = (float*)d_ws;
  const int n = in_sizes[0];

  int nblk = 1024;
  size_t need = (size_t)(nblk * RED_VALS + 64) * sizeof(float);
  if (ws_size < need) {
    long avail = (long)(ws_size / sizeof(float)) - 64;
    nblk = (int)(avail / RED_VALS);
    if (nblk < 1) nblk = 1;
    if (nblk > 1024) nblk = 1024;
  }
  float* partials = wsf;
  float* coeff = wsf + (size_t)nblk * RED_VALS;

  lbfgs_reduce<<<dim3(nblk), dim3(256), 0, stream>>>(p, y, g, idxp, partials, n);
  lbfgs_solve<<<dim3(1), dim3(256), 0, stream>>>(partials, nblk, Lmat, diag,
                                                 sinner, idxp, coeff);
  lbfgs_output<<<dim3(nblk), dim3(256), 0, stream>>>(p, y, g, coeff, out, n);
}

// Round 2
// 236.456 us; speedup vs baseline: 1.0930x; 1.0930x over previous
//
#include <hip/hip_runtime.h>

#define HH 16
#define GX 256        // reduce grid.x (slab blocks per history row)
#define RED_VALS 34   // 16 top(g.p) + 16 (y.p) + cur + gg

// One history row per blockIdx.y: low register pressure, high occupancy,
// pure streaming of g_row / y_row; p is re-read per row but lives in L3.
__global__ __launch_bounds__(256) void lbfgs_reduce(
    const float* __restrict__ p, const float* __restrict__ y,
    const float* __restrict__ g, const int* __restrict__ idxp,
    float* __restrict__ partials, int n) {
  const int row = blockIdx.y;
  const int is = idxp[0];
  const int hidx = ((is - 1) % HH + HH) % HH;
  const bool special = (row == hidx);

  const float4* __restrict__ p4 = reinterpret_cast<const float4*>(p);
  const float4* __restrict__ g4 = reinterpret_cast<const float4*>(g + (size_t)row * n);
  const float4* __restrict__ y4 = reinterpret_cast<const float4*>(y + (size_t)row * n);

  float ag = 0.f, ay = 0.f, ac = 0.f, agg = 0.f;
  const int tid = blockIdx.x * blockDim.x + threadIdx.x;
  const int nth = gridDim.x * blockDim.x;
  const int nchunk = n >> 2;

  for (int c = tid; c < nchunk; c += nth) {
    float4 pv = p4[c];
    float4 gv = g4[c];
    float4 yv = y4[c];
    ag += gv.x * pv.x + gv.y * pv.y + gv.z * pv.z + gv.w * pv.w;
    ay += yv.x * pv.x + yv.y * pv.y + yv.z * pv.z + yv.w * pv.w;
    if (special) {
      ac  += yv.x * gv.x + yv.y * gv.y + yv.z * gv.z + yv.w * gv.w;
      agg += gv.x * gv.x + gv.y * gv.y + gv.z * gv.z + gv.w * gv.w;
    }
  }
  // scalar tail (n not multiple of 4)
  for (int c = (nchunk << 2) + tid; c < n; c += nth) {
    float pv = p[c];
    float gv = g[(size_t)row * n + c];
    float yv = y[(size_t)row * n + c];
    ag += gv * pv;
    ay += yv * pv;
    if (special) { ac += yv * gv; agg += gv * gv; }
  }

  // block-reduce 4 values: wave shuffle then cross-wave LDS
  float vals[4] = {ag, ay, ac, agg};
#pragma unroll
  for (int j = 0; j < 4; ++j) {
    float v = vals[j];
#pragma unroll
    for (int off = 32; off > 0; off >>= 1) v += __shfl_down(v, off);
    vals[j] = v;
  }
  __shared__ float red[4][4];
  const int wave = threadIdx.x >> 6, lane = threadIdx.x & 63;
  if (lane == 0) {
#pragma unroll
    for (int j = 0; j < 4; ++j) red[wave][j] = vals[j];
  }
  __syncthreads();
  if (threadIdx.x < 4) {
    float s = red[0][threadIdx.x] + red[1][threadIdx.x] +
              red[2][threadIdx.x] + red[3][threadIdx.x];
    partials[((size_t)row * gridDim.x + blockIdx.x) * 4 + threadIdx.x] = s;
  }
}

__global__ __launch_bounds__(256) void lbfgs_solve(
    const float* __restrict__ partials, int nblkx,
    const float* __restrict__ Lmat, const float* __restrict__ diag,
    const float* __restrict__ sinner, const int* __restrict__ idxp,
    float* __restrict__ coeff) {
  const int is = idxp[0];
  const int hidx = ((is - 1) % HH + HH) % HH;
  __shared__ float sums[RED_VALS];
  __shared__ float wred[RED_VALS][4];
  const int wave = threadIdx.x >> 6, lane = threadIdx.x & 63;
  for (int j = 0; j < RED_VALS; ++j) {
    const int row  = (j < HH) ? j : (j < 2 * HH ? j - HH : hidx);
    const int comp = (j < HH) ? 0 : (j < 2 * HH ? 1 : (j == 32 ? 2 : 3));
    float v = 0.f;
    for (int b = threadIdx.x; b < nblkx; b += 256)
      v += partials[((size_t)row * nblkx + b) * 4 + comp];
#pragma unroll
    for (int off = 32; off > 0; off >>= 1) v += __shfl_down(v, off);
    if (lane == 0) wred[j][wave] = v;
  }
  __syncthreads();
  if (threadIdx.x < RED_VALS)
    sums[threadIdx.x] = wred[threadIdx.x][0] + wred[threadIdx.x][1] +
                        wred[threadIdx.x][2] + wred[threadIdx.x][3];
  __syncthreads();

  __shared__ float Lsh[HH][HH];
  __shared__ float dd[HH], sqd[HH];
  __shared__ float Jsq[HH][HH];
  __shared__ float gamma_s;
  __shared__ float x[2 * HH];
  {
    int i = threadIdx.x >> 4, j = threadIdx.x & 15;
    if (threadIdx.x < 256) Lsh[i][j] = Lmat[i * HH + j];
  }
  if (threadIdx.x < HH) {
    float dv = diag[threadIdx.x];
    float ddv = (dv == 0.f) ? 1.f : dv;
    dd[threadIdx.x] = ddv;
    sqd[threadIdx.x] = sqrtf(ddv);
  }
  if (threadIdx.x == 0) {
    float cur = sums[32], gg = sums[33];
    gamma_s = (cur > 0.f) ? (gg / cur) : 1.f;
  }
  __syncthreads();
  {
    int i = threadIdx.x >> 4, j = threadIdx.x & 15;
    float v = gamma_s * sinner[i * HH + j];
#pragma unroll
    for (int k = 0; k < HH; ++k) v += Lsh[i][k] * Lsh[j][k] / dd[k];
    Jsq[i][j] = v;
  }
  __syncthreads();
  if (threadIdx.x == 0) {
    // in-place lower Cholesky of Jsq (16x16, serial — tiny)
    for (int c = 0; c < HH; ++c) {
      float s = Jsq[c][c];
      for (int k = 0; k < c; ++k) s -= Jsq[c][k] * Jsq[c][k];
      float dv = sqrtf(s);
      Jsq[c][c] = dv;
      float inv = 1.f / dv;
      for (int r = c + 1; r < HH; ++r) {
        float s2 = Jsq[r][c];
        for (int k = 0; k < c; ++k) s2 -= Jsq[r][k] * Jsq[c][k];
        Jsq[r][c] = s2 * inv;
      }
    }
    const int sh = (is <= HH) ? 0 : (is % HH);
    const float gamma = gamma_s;
    // build rolled descent vector
    for (int k = 0; k < HH; ++k) {
      x[k]      = sums[(k + sh) & (HH - 1)];
      x[HH + k] = gamma * sums[HH + ((k + sh) & (HH - 1))];
    }
    // forward solve: low_tri = [[diag(sqd), 0], [-L/sqd_col, J]]
    for (int i = 0; i < HH; ++i) x[i] /= sqd[i];
    for (int i = 0; i < HH; ++i) {
      float s = x[HH + i];
      for (int j = 0; j < HH; ++j) s += (Lsh[i][j] / sqd[j]) * x[j];
      for (int j = 0; j < i; ++j) s -= Jsq[i][j] * x[HH + j];
      x[HH + i] = s / Jsq[i][i];
    }
    // backward solve: upper = low^T with top h rows negated
    for (int i = HH - 1; i >= 0; --i) {
      float s = x[HH + i];
      for (int j = i + 1; j < HH; ++j) s -= Jsq[j][i] * x[HH + j];
      x[HH + i] = s / Jsq[i][i];
    }
    for (int i = 0; i < HH; ++i) {
      float s = x[i];
      for (int j = 0; j < HH; ++j) s -= (Lsh[j][i] / sqd[i]) * x[HH + j];
      x[i] = s / (-sqd[i]);
    }
    // un-roll and emit coefficients (beta pre-scaled by gamma)
    coeff[0] = gamma;
    for (int k = 0; k < HH; ++k) {
      coeff[1 + k]      = x[(k - sh + HH) & (HH - 1)];
      coeff[1 + HH + k] = gamma * x[HH + ((k - sh + HH) & (HH - 1))];
    }
  }
}

__global__ __launch_bounds__(256) void lbfgs_output(
    const float* __restrict__ p, const float* __restrict__ y,
    const float* __restrict__ g, const float* __restrict__ coeff,
    float* __restrict__ out, int n) {
  const float gamma = coeff[0];
  float a[HH], b[HH];
#pragma unroll
  for (int i = 0; i < HH; ++i) {
    a[i] = coeff[1 + i];
    b[i] = coeff[1 + HH + i];
  }
  const int tid = blockIdx.x * blockDim.x + threadIdx.x;
  const int nth = gridDim.x * blockDim.x;
  const int nchunk = n >> 2;
  const float4* __restrict__ p4 = reinterpret_cast<const float4*>(p);
  float4* __restrict__ out4 = reinterpret_cast<float4*>(out);
  for (int c = tid; c < nchunk; c += nth) {
    float4 pv = p4[c];
    float ox = gamma * pv.x, oy = gamma * pv.y;
    float oz = gamma * pv.z, ow = gamma * pv.w;
#pragma unroll
    for (int i = 0; i < HH; ++i) {
      const float4 gv = reinterpret_cast<const float4*>(g + (size_t)i * n)[c];
      const float4 yv = reinterpret_cast<const float4*>(y + (size_t)i * n)[c];
      ox -= a[i] * gv.x + b[i] * yv.x;
      oy -= a[i] * gv.y + b[i] * yv.y;
      oz -= a[i] * gv.z + b[i] * yv.z;
      ow -= a[i] * gv.w + b[i] * yv.w;
    }
    out4[c] = make_float4(ox, oy, oz, ow);
  }
  for (int c = (nchunk << 2) + tid; c < n; c += nth) {
    float pv = p[c];
    float o = gamma * pv;
#pragma unroll
    for (int i = 0; i < HH; ++i)
      o -= a[i] * g[(size_t)i * n + c] + b[i] * y[(size_t)i * n + c];
    out[c] = o;
  }
}

extern "C" void kernel_launch(void* const* d_in, const int* in_sizes, int n_in,
                              void* d_out, int out_size, void* d_ws, size_t ws_size,
                              hipStream_t stream) {
  const float* p      = (const float*)d_in[0];
  const float* y      = (const float*)d_in[1];
  const float* g      = (const float*)d_in[2];
  const float* Lmat   = (const float*)d_in[3];
  const float* diag   = (const float*)d_in[4];
  const float* sinner = (const float*)d_in[5];
  const int*   idxp   = (const int*)d_in[6];
  float* out = (float*)d_out;
  float* wsf = (float*)d_ws;
  const int n = in_sizes[0];

  int gx = GX;
  size_t need = ((size_t)HH * gx * 4 + 64) * sizeof(float);
  if (ws_size < need) {
    long avail = (long)(ws_size / sizeof(float)) - 64;
    gx = (int)(avail / (HH * 4));
    if (gx < 1) gx = 1;
    if (gx > GX) gx = GX;
  }
  float* partials = wsf;
  float* coeff = wsf + (size_t)HH * gx * 4;

  lbfgs_reduce<<<dim3(gx, HH), dim3(256), 0, stream>>>(p, y, g, idxp, partials, n);
  lbfgs_solve<<<dim3(1), dim3(256), 0, stream>>>(partials, gx, Lmat, diag,
                                                 sinner, idxp, coeff);
  lbfgs_output<<<dim3(2048), dim3(256), 0, stream>>>(p, y, g, coeff, out, n);
}